// Round 2
// baseline (127.304 us; speedup 1.0000x reference)
//
#include <hip/hip_runtime.h>
#include <hip/hip_fp16.h>

// Shape: b=4, t_q=128, t_k=512, n=512, out=512. All fp32 in/out.
// Output: [out (4*128*512), probs (4*128*512)].
//
// Round-16 (on round-15): fold attq into pack_kernel; 3 launches total.
//  Round-15 lesson: weight phases were NOT L2-BW-bound (80MB/XCD amortized
//  under phase drift); the 4-kernel split paid 2 launches (~1.2us each) for
//  ~no kernel-time win. attq is independent of pack outputs if it reads raw
//  fp32 query/W_q -> run it as 256 compute-bound blocks INSIDE pack_kernel
//  (bx 0..255, dispatched first, VALU work overlaps pack's mem-bound
//  blocks). W_qP packing dropped entirely. attq accumulates in fp32 now
//  (more accurate than old fp16-fdot2 -> absmax can only improve).
//  attn_mid / out_kernel byte-identical to round-15.

#define BB    4
#define TQ    128
#define TK    512
#define NN    512
#define OUTSZ 512
#define CATSZ 1024
#define K2E   2.8853900817779268f   // 2*log2(e)
#define L2E   1.4426950408889634f   // log2(e)
#define MAT   262144                // 512*512
// ws halves: keysE[0,4M) [4M,5M unused] W_outP[5M,7M) valuesP[7M,11M)
//            catG[11M,13M) pawG[13M,15M)
#define WS_HALVES (15 * MAT)

typedef __attribute__((ext_vector_type(4))) _Float16 half4;
typedef __attribute__((ext_vector_type(8))) _Float16 half8;
typedef __attribute__((ext_vector_type(2))) _Float16 h2;

#if __has_builtin(__builtin_amdgcn_exp2f)
#define EXP2F(x) __builtin_amdgcn_exp2f(x)
#else
#define EXP2F(x) exp2f(x)
#endif
#if __has_builtin(__builtin_amdgcn_rcpf)
#define RCPF(x) __builtin_amdgcn_rcpf(x)
#else
#define RCPF(x) (1.0f / (x))
#endif

__device__ __forceinline__ h2 u2h(unsigned int u) {
  union { unsigned int i; h2 h; } v; v.i = u; return v.h;
}
__device__ __forceinline__ half4 uu2h4(unsigned int a, unsigned int b) {
  union { uint2 u; half4 h; } c; c.u = make_uint2(a, b); return c.h;
}
#if __has_builtin(__builtin_amdgcn_fdot2)
__device__ __forceinline__ float FDOT2(h2 a, h2 b, float c) {
  return __builtin_amdgcn_fdot2(a, b, c, false);
}
#else
__device__ __forceinline__ float FDOT2(h2 a, h2 b, float c) {
  return fmaf((float)a.x, (float)b.x, fmaf((float)a.y, (float)b.y, c));
}
#endif

__device__ __forceinline__ float fast_tanh(float x) {
  float e = EXP2F(x * K2E);
  return fmaf(-2.0f, RCPF(e + 1.0f), 1.0f);
}
__device__ __forceinline__ float waveRedSum(float s) {
  #pragma unroll
  for (int m = 32; m >= 1; m >>= 1) s += __shfl_xor(s, m, 64);
  return s;
}
__device__ __forceinline__ float fma4(float4 w, float4 v, float acc) {
  acc = fmaf(w.x, v.x, acc); acc = fmaf(w.y, v.y, acc);
  acc = fmaf(w.z, v.z, acc); acc = fmaf(w.w, v.w, acc);
  return acc;
}
// score quad: s[i] += w * rcp(E_h[i]*A + 1)
__device__ __forceinline__ float4 scqh(float4 s, half4 E, float A, float w) {
  s.x = fmaf(w, RCPF(fmaf((float)E.x, A, 1.0f)), s.x);
  s.y = fmaf(w, RCPF(fmaf((float)E.y, A, 1.0f)), s.y);
  s.z = fmaf(w, RCPF(fmaf((float)E.z, A, 1.0f)), s.z);
  s.w = fmaf(w, RCPF(fmaf((float)E.w, A, 1.0f)), s.w);
  return s;
}
// paired-GEMM micro-op: 8 fdot2 for 4 outputs x 2 rows, one contraction pair
__device__ __forceinline__ void dotq(float4& r0, float4& r1, uint4 wp, unsigned int cpa, unsigned int cpb) {
  h2 c0 = u2h(cpa), c1 = u2h(cpb);
  r0.x = FDOT2(u2h(wp.x), c0, r0.x); r1.x = FDOT2(u2h(wp.x), c1, r1.x);
  r0.y = FDOT2(u2h(wp.y), c0, r0.y); r1.y = FDOT2(u2h(wp.y), c1, r1.y);
  r0.z = FDOT2(u2h(wp.z), c0, r0.z); r1.z = FDOT2(u2h(wp.z), c1, r1.z);
  r0.w = FDOT2(u2h(wp.w), c0, r0.w); r1.w = FDOT2(u2h(wp.w), c1, r1.w);
}

// ---------------- pack kernel (+ attq + query->catG pairs) -------------------
// grid 3072, 256 threads:
//  [0,256)     attq blocks: pawG = {A0,A1,w,0}  (fp32 GEMM from raw W_q/query)
//  [256,1280)  keysE: transpose + exp2
//  [1280,2304) valuesP: fp16 k-pair pack
//  [2304,2816) W_outP: fp16 pair pack
//  [2816,3072) query -> catG query-half pairs
__global__ __launch_bounds__(256)
void pack_kernel(const float* __restrict__ query,
                 const float* __restrict__ keys, const float* __restrict__ W_q,
                 const float* __restrict__ W_out, const float* __restrict__ values,
                 const float* __restrict__ b_q, const float* __restrict__ w_att,
                 _Float16* __restrict__ ws)
{
  __shared__ __align__(16) float smem[8 * 512];   // 16 KB, aliased below
  float (*tile)[33] = (float (*)[33])smem;        // 32x33 fits (4.2 KB)
  float (*qlds)[512] = (float (*)[512])smem;      // 8x512 (attq staging)

  const int idx = blockIdx.x;
  const int tx = threadIdx.x & 31, ty = threadIdx.x >> 5;   // 32x8

  if (idx < 256) {                        // attq: dispatched FIRST (overlap)
    // block (pg = idx>>2, ng = idx&3): qpairs [4pg,+4) x n [128ng,+128)
    {
      int i = threadIdx.x >> 5;           // staged row 0..7
      int d0 = (threadIdx.x & 31) * 16;
      int p = 4 * (idx >> 2) + (i >> 1);
      int bb = (p & 7) >> 1;
      int qg = ((p >> 3) << 1) | (p & 1);
      const float4* qr =
          (const float4*)(query + ((size_t)(bb * TQ + qg * 2 + (i & 1))) * NN + d0);
      float4* dst4 = (float4*)&qlds[i][d0];
      dst4[0] = qr[0]; dst4[1] = qr[1]; dst4[2] = qr[2]; dst4[3] = qr[3];
    }
    __syncthreads();
    const int ng = idx & 3, pg = idx >> 2;
    const int n = 128 * ng + (threadIdx.x & 127);
    const int rh = threadIdx.x >> 7;      // rows 4rh..4rh+3 (wave-uniform)
    const float4* wr = (const float4*)(W_q + (size_t)n * NN);
    const float4* q0 = (const float4*)qlds[4 * rh + 0];
    const float4* q1 = (const float4*)qlds[4 * rh + 1];
    const float4* q2 = (const float4*)qlds[4 * rh + 2];
    const float4* q3 = (const float4*)qlds[4 * rh + 3];
    float a0 = 0.f, a1 = 0.f, a2 = 0.f, a3 = 0.f;
    #pragma unroll 4
    for (int d4 = 0; d4 < 128; ++d4) {
      float4 w4 = wr[d4];
      a0 = fma4(w4, q0[d4], a0);
      a1 = fma4(w4, q1[d4], a1);
      a2 = fma4(w4, q2[d4], a2);
      a3 = fma4(w4, q3[d4], a3);
    }
    float bq = b_q[n], wa = w_att[n];
    _Float16* pawG = ws + (size_t)13 * MAT;
    {
      float A0 = EXP2F(K2E * (a0 + bq));
      float A1 = EXP2F(K2E * (a1 + bq));
      half4 h = {(_Float16)A0, (_Float16)A1, (_Float16)wa, (_Float16)0.f};
      *(half4*)(pawG + (size_t)(4 * pg + 2 * rh) * 2048 + 4 * n) = h;
    }
    {
      float A0 = EXP2F(K2E * (a2 + bq));
      float A1 = EXP2F(K2E * (a3 + bq));
      half4 h = {(_Float16)A0, (_Float16)A1, (_Float16)wa, (_Float16)0.f};
      *(half4*)(pawG + (size_t)(4 * pg + 2 * rh + 1) * 2048 + 4 * n) = h;
    }
    return;
  }

  if (idx >= 2816) {                      // query -> catG query-half (pairs)
    int p = idx - 2816;                   // qpair id (== attn_mid blockIdx)
    int b = (p & 7) >> 1;
    int qg = ((p >> 3) << 1) | (p & 1);
    const float* q0 = query + ((size_t)(b * TQ + qg * 2)) * NN;
    const float* q1 = q0 + NN;
    int cp = threadIdx.x;                 // 0..255 (c-pair)
    float2 a = *(const float2*)(q0 + 2 * cp);
    float2 c = *(const float2*)(q1 + 2 * cp);
    // layout: catG[p][cp*4 + row*2 + (c&1)]
    half4 h = {(_Float16)a.x, (_Float16)a.y, (_Float16)c.x, (_Float16)c.y};
    *(half4*)(ws + (size_t)11 * MAT + (size_t)p * 2048 + 4 * cp) = h;
    return;
  }

  if (idx >= 1280 && idx < 2304) {        // valuesP: 1024 blocks, 2 k-rows each
    int r = idx - 1280;
    int b = r >> 8, k2 = r & 255;
    const float* r0 = values + ((size_t)b * 512 + 2 * k2) * 512;
    const float* r1 = r0 + 512;
    int n0 = threadIdx.x * 2;
    float2 a = *(const float2*)(r0 + n0);
    float2 c = *(const float2*)(r1 + n0);
    _Float16* dst = ws + (size_t)7 * MAT + (size_t)b * MAT + k2 * 1024 + n0 * 2;
    half4 h = {(_Float16)a.x, (_Float16)c.x, (_Float16)a.y, (_Float16)c.y};
    *(half4*)dst = h;
    return;
  }

  if (idx < 1280) {                       // keysE: transpose + exp2
    int r2 = idx - 256;
    int b = r2 >> 8, r = r2 & 255;
    int by = r >> 4, bx = r & 15;
    const float* src = keys + (size_t)b * MAT;
    _Float16* dst = ws + (size_t)b * MAT;
    #pragma unroll
    for (int i = 0; i < 32; i += 8)
      tile[ty + i][tx] = src[(size_t)(by * 32 + ty + i) * 512 + bx * 32 + tx] * K2E;
    __syncthreads();
    #pragma unroll
    for (int i = 0; i < 32; i += 8)
      dst[(size_t)(bx * 32 + ty + i) * 512 + by * 32 + tx] = (_Float16)EXP2F(tile[tx][ty + i]);
    return;
  }

  {                                       // W_outP: 512 blocks
    int r = idx - 2304;
    int by = r >> 5, bx = r & 31;
    const float* src = W_out;
    _Float16* dst = ws + (size_t)5 * MAT;
    #pragma unroll
    for (int i = 0; i < 32; i += 8)
      tile[ty + i][tx] = src[(size_t)(by * 32 + ty + i) * 1024 + bx * 32 + tx];
    __syncthreads();
    #pragma unroll
    for (int i = 0; i < 32; i += 8) {
      int d = bx * 32 + ty + i;           // contraction index c
      int o = by * 32 + tx;               // output index o
      dst[(size_t)(d >> 1) * 1024 + o * 2 + (d & 1)] = (_Float16)tile[tx][ty + i];
    }
  }
}

// ---------------- attn_mid: scores + softmax + context -----------------------
__global__ __launch_bounds__(1024, 4)
void attn_mid(_Float16* __restrict__ ws, float* __restrict__ probs)
{
  __shared__ __align__(16) _Float16 pawF[NN * 4]; // {A0,A1,w,pad} per n, 4 KB
  __shared__ __align__(16) _Float16 prH[1024];    // probs pairs, 2 KB
  __shared__ __align__(16) float  pt[8][2][NN];   // partial scratch 32 KB
  __shared__ float reds2[2][8];

  _Float16* ptH = (_Float16*)pt;                  // fp16 view: ptH[qh][G16][k]

  const _Float16* wsKeys = ws;
  const _Float16* wsValP = ws + (size_t)7 * MAT;
  _Float16* catG         = ws + (size_t)11 * MAT;
  const _Float16* pawG   = ws + (size_t)13 * MAT;

  const int t    = threadIdx.x;        // 0..1023
  const int qh   = t >> 9;             // combine-phase q row (0/1)
  const int u    = t & 511;            // combine-phase index
  const int G    = t >> 7;             // contraction range 0..7 (wave-uniform)
  const int v    = t & 127;            // output quad index (4v..4v+3)
  const int G16  = t >> 6;             // step-2 contraction range 0..15 (=wave)
  const int v6   = t & 63;             // step-2 k-oct index (8*v6 .. +8) (=lane)
  const int wave = t >> 6, lane = t & 63, wq8 = wave & 7;

  const int p  = blockIdx.x;                 // 0..255 (XCD swizzle)
  const int b  = (p & 7) >> 1;
  const int qg = ((p >> 3) << 1) | (p & 1);
  const int qabs0 = qg * 2;

  // ---- stage: pawG -> pawF (4 KB) ----
  ((unsigned int*)pawF)[t] = ((const unsigned int*)(pawG + (size_t)p * 2048))[t];
  __syncthreads();

  // ---- step 2 (hot): score partials, k-OCT per thread.
  {
    const _Float16* ke = wsKeys + (size_t)b * MAT + 8 * v6;
    float4 s0a = {0,0,0,0}, s0b = {0,0,0,0};
    float4 s1a = {0,0,0,0}, s1b = {0,0,0,0};
    #pragma unroll 2
    for (int j = 0; j < 32; j += 2) {
      int n = 32 * G16 + j;
      uint4 Eu0 = *(const uint4*)(ke + (size_t)n * 512);
      uint4 Eu1 = *(const uint4*)(ke + (size_t)(n + 1) * 512);
      uint4 pw  = *(const uint4*)(&pawF[n * 4]);   // {A0,A1,w,pad}x2
      h2 Aab = u2h(pw.x);  float w0f = (float)u2h(pw.y).x;
      h2 Acd = u2h(pw.z);  float w1f = (float)u2h(pw.w).x;
      float A0n = (float)Aab.x, A1n = (float)Aab.y;
      float A0m = (float)Acd.x, A1m = (float)Acd.y;
      half4 E0lo = uu2h4(Eu0.x, Eu0.y), E0hi = uu2h4(Eu0.z, Eu0.w);
      half4 E1lo = uu2h4(Eu1.x, Eu1.y), E1hi = uu2h4(Eu1.z, Eu1.w);
      s0a = scqh(s0a, E0lo, A0n, w0f);
      s0b = scqh(s0b, E0hi, A0n, w0f);
      s1a = scqh(s1a, E0lo, A1n, w0f);
      s1b = scqh(s1b, E0hi, A1n, w0f);
      s0a = scqh(s0a, E1lo, A0m, w1f);
      s0b = scqh(s0b, E1hi, A0m, w1f);
      s1a = scqh(s1a, E1lo, A1m, w1f);
      s1b = scqh(s1b, E1hi, A1m, w1f);
    }
    half8 w0 = {(_Float16)s0a.x, (_Float16)s0a.y, (_Float16)s0a.z, (_Float16)s0a.w,
                (_Float16)s0b.x, (_Float16)s0b.y, (_Float16)s0b.z, (_Float16)s0b.w};
    half8 w1 = {(_Float16)s1a.x, (_Float16)s1a.y, (_Float16)s1a.z, (_Float16)s1a.w,
                (_Float16)s1b.x, (_Float16)s1b.y, (_Float16)s1b.z, (_Float16)s1b.w};
    *(half8*)(ptH + (size_t)G16 * 512 + 8 * v6)        = w0;
    *(half8*)(ptH + 8192 + (size_t)G16 * 512 + 8 * v6) = w1;
  }
  __syncthreads();

  // ---- softmax (no max-subtraction; batt+sumW cancels): thread (qh,u), k=u.
  {
    const _Float16* pp = ptH + qh * 8192 + u;   // stride 512 halves over G16
    float s = 0.f;
    #pragma unroll
    for (int g = 0; g < 16; ++g)
      s += (float)pp[g * 512];
    float e = EXP2F(-K2E * s);           // softmax weight (constants cancel)
    float se = waveRedSum(e);
    if (lane == 0) reds2[qh][wq8] = se;
    __syncthreads();
    float bs = reds2[qh][0]+reds2[qh][1]+reds2[qh][2]+reds2[qh][3]
             + reds2[qh][4]+reds2[qh][5]+reds2[qh][6]+reds2[qh][7];
    float pv = e * RCPF(bs);
    prH[(u >> 1) * 4 + qh * 2 + (u & 1)] = (_Float16)pv;
    probs[((size_t)(b * TQ + qabs0 + qh)) * TK + u] = pv;
  }
  __syncthreads();

  // ---- step 4: context partials via fdot2.  Thread (G,v): n quad 4v, k2 in [32G,+32).
  {
    const _Float16* vp = wsValP + (size_t)b * MAT + 8 * v;
    float4 c0 = {0,0,0,0}, c1 = {0,0,0,0};
    #pragma unroll 2
    for (int j2 = 0; j2 < 32; j2 += 2) {
      int k2 = 32 * G + j2;
      uint4 vk0 = *(const uint4*)(vp + (size_t)k2 * 1024);
      uint4 vk1 = *(const uint4*)(vp + (size_t)(k2 + 1) * 1024);
      uint4 pp2 = *(const uint4*)(&prH[k2 * 4]);
      dotq(c0, c1, vk0, pp2.x, pp2.y);
      dotq(c0, c1, vk1, pp2.z, pp2.w);
    }
    *(float4*)(&pt[G][0][4 * v]) = c0;
    *(float4*)(&pt[G][1][4 * v]) = c1;
  }
  __syncthreads();
  {
    float s = pt[0][qh][u] + pt[1][qh][u] + pt[2][qh][u] + pt[3][qh][u]
            + pt[4][qh][u] + pt[5][qh][u] + pt[6][qh][u] + pt[7][qh][u];
    // catG ctx-half, same pair layout as round-14's catH
    catG[(size_t)p * 2048 + (size_t)(256 + (u >> 1)) * 4 + qh * 2 + (u & 1)] =
        (_Float16)s;
  }
}

// ---------------- out kernel: out = tanh(cat . W_out^T + b_out) --------------
// grid 256: block (pg = bx>>2, og = bx&3): qpairs [4pg,+4) x out [128og,+128)
// XCD = bx%8 -> og fixed per XCD -> each XCD streams ONE 256KB W_out quarter.
__global__ __launch_bounds__(1024, 4)
void out_kernel(const float* __restrict__ b_out, const _Float16* __restrict__ ws,
                float* __restrict__ out)
{
  __shared__ __align__(16) _Float16 ldsCat[8192];    // 16 KB: 4 qpairs x 2048
  __shared__ __align__(16) float pt[8][4][2][128];   // 32 KB

  const _Float16* wsWoutP = ws + (size_t)5 * MAT;
  const _Float16* catG    = ws + (size_t)11 * MAT;

  const int t = threadIdx.x, bx = blockIdx.x;
  const int og = bx & 3, pg = bx >> 2;

  // stage cat for 4 qpairs (contiguous in catG): 8192 halves = 1024 uint4
  ((uint4*)ldsCat)[t] = ((const uint4*)(catG + (size_t)4 * pg * 2048))[t];
  __syncthreads();

  const int G = t >> 7, pq = (t >> 5) & 3, v5 = t & 31;
  {
    const _Float16* wo = wsWoutP + 8 * (32 * og + v5);
    float4 o0 = {0,0,0,0}, o1 = {0,0,0,0};
    #pragma unroll 2
    for (int j2 = 0; j2 < 64; j2 += 2) {
      int c2 = 64 * G + j2;
      uint4 wp0 = *(const uint4*)(wo + (size_t)c2 * 1024);
      uint4 wp1 = *(const uint4*)(wo + (size_t)(c2 + 1) * 1024);
      uint4 cp2 = *(const uint4*)(&ldsCat[pq * 2048 + c2 * 4]);
      dotq(o0, o1, wp0, cp2.x, cp2.y);
      dotq(o0, o1, wp1, cp2.z, cp2.w);
    }
    *(float4*)(&pt[G][pq][0][4 * v5]) = o0;
    *(float4*)(&pt[G][pq][1][4 * v5]) = o1;
  }
  __syncthreads();
  {
    int pq2 = t >> 8, row = (t >> 7) & 1, oo = t & 127;
    float s = pt[0][pq2][row][oo] + pt[1][pq2][row][oo]
            + pt[2][pq2][row][oo] + pt[3][pq2][row][oo]
            + pt[4][pq2][row][oo] + pt[5][pq2][row][oo]
            + pt[6][pq2][row][oo] + pt[7][pq2][row][oo];
    int o = 128 * og + oo;
    int p = 4 * pg + pq2;
    int b = (p & 7) >> 1;
    int qg = ((p >> 3) << 1) | (p & 1);
    out[((size_t)(b * TQ + qg * 2 + row)) * OUTSZ + o] = fast_tanh(s + b_out[o]);
  }
}

// ---------------- round-6-style fallback (ws too small) ----------------------
__device__ __forceinline__ float sc4f(float4 w, float4 k, float4 a, float acc) {
  acc = fmaf(w.x, RCPF(EXP2F(fmaf(k.x, K2E, a.x)) + 1.0f), acc);
  acc = fmaf(w.y, RCPF(EXP2F(fmaf(k.y, K2E, a.y)) + 1.0f), acc);
  acc = fmaf(w.z, RCPF(EXP2F(fmaf(k.z, K2E, a.z)) + 1.0f), acc);
  acc = fmaf(w.w, RCPF(EXP2F(fmaf(k.w, K2E, a.w)) + 1.0f), acc);
  return acc;
}

__global__ __launch_bounds__(1024, 4)
void attn_fallback(const float* __restrict__ query, const float* __restrict__ keys,
                   const float* __restrict__ values, const float* __restrict__ W_q,
                   const float* __restrict__ b_q, const float* __restrict__ w_att,
                   const float* __restrict__ b_att, const float* __restrict__ W_out,
                   const float* __restrict__ b_out,
                   float* __restrict__ out, float* __restrict__ probs)
{
  __shared__ __align__(16) float qv[2][NN];
  __shared__ __align__(16) float aqc[2][NN];
  __shared__ __align__(16) float wv[NN];
  __shared__ __align__(16) float pr[2][TK];
  __shared__ __align__(16) float ctx[2][NN];
  __shared__ __align__(16) float part[2][2][NN];
  __shared__ float redm[2][8], reds[2][8], redw[8];

  const int t = threadIdx.x, H = t >> 9, u = t & 511;
  const int wave = t >> 6, lane = t & 63, wq8 = wave & 7;
  const int p = blockIdx.x, b = (p & 7) >> 1;
  const int qg = ((p >> 3) << 1) | (p & 1), qabs0 = qg * 2;
  const float batt = b_att[0];

  if (H == 0) wv[u] = w_att[u];
  qv[H][u] = query[((size_t)(b * TQ + qabs0 + H)) * NN + u];
  __syncthreads();
  if (H == 0) {
    float wp = waveRedSum(wv[u]);
    if (lane == 0) redw[wq8] = wp;
  }
  __syncthreads();
  const float sumW = redw[0]+redw[1]+redw[2]+redw[3]+redw[4]+redw[5]+redw[6]+redw[7];

  {
    const float4* wq4 = (const float4*)(W_q + (size_t)u * NN + 256 * H);
    const float4* x4  = (const float4*)(qv[0] + 256 * H);
    const float4* y4  = (const float4*)(qv[1] + 256 * H);
    float a0=0.f, a0b=0.f, a1=0.f, a1b=0.f;
    #pragma unroll 2
    for (int c = 0; c < 16; ++c) {
      float4 wA=wq4[4*c+0], wB=wq4[4*c+1], wC=wq4[4*c+2], wD=wq4[4*c+3];
      float4 xA=x4[4*c+0], xB=x4[4*c+1], xC=x4[4*c+2], xD=x4[4*c+3];
      a0 = fma4(wA,xA,a0); a0b = fma4(wB,xB,a0b);
      a0 = fma4(wC,xC,a0); a0b = fma4(wD,xD,a0b);
      float4 yA=y4[4*c+0], yB=y4[4*c+1], yC=y4[4*c+2], yD=y4[4*c+3];
      a1 = fma4(wA,yA,a1); a1b = fma4(wB,yB,a1b);
      a1 = fma4(wC,yC,a1); a1b = fma4(wD,yD,a1b);
    }
    part[H][0][u] = a0 + a0b; part[H][1][u] = a1 + a1b;
  }
  __syncthreads();
  aqc[H][u] = (part[0][H][u] + part[1][H][u] + b_q[u]) * K2E;
  __syncthreads();

  {
    const float4* kr  = (const float4*)(keys + ((size_t)(b * TK) + u) * NN + 256 * H);
    const float4* a0p = (const float4*)(aqc[0] + 256 * H);
    const float4* a1p = (const float4*)(aqc[1] + 256 * H);
    const float4* w4  = (const float4*)(wv + 256 * H);
    float s0 = 0.f, s1 = 0.f;
    #pragma unroll 2
    for (int c = 0; c < 16; ++c) {
      float4 kA=kr[4*c+0], kB=kr[4*c+1], kC=kr[4*c+2], kD=kr[4*c+3];
      float4 wA=w4[4*c+0], wB=w4[4*c+1], wC=w4[4*c+2], wD=w4[4*c+3];
      float4 aA=a0p[4*c+0], aB=a0p[4*c+1], aC=a0p[4*c+2], aD=a0p[4*c+3];
      s0 = sc4f(wA,kA,aA,s0); s0 = sc4f(wB,kB,aB,s0);
      s0 = sc4f(wC,kC,aC,s0); s0 = sc4f(wD,kD,aD,s0);
      float4 bA=a1p[4*c+0], bB=a1p[4*c+1], bC=a1p[4*c+2], bD=a1p[4*c+3];
      s1 = sc4f(wA,kA,bA,s1); s1 = sc4f(wB,kB,bB,s1);
      s1 = sc4f(wC,kC,bC,s1); s1 = sc4f(wD,kD,bD,s1);
    }
    part[H][0][u] = s0; part[H][1][u] = s1;
  }
  __syncthreads();

  {
    float sc = batt + sumW - 2.0f * (part[0][H][u] + part[1][H][u]);
    float m = sc;
    #pragma unroll
    for (int mm = 32; mm >= 1; mm >>= 1) m = fmaxf(m, __shfl_xor(m, mm, 64));
    if (lane == 0) redm[H][wq8] = m;
    __syncthreads();
    float bm = fmaxf(fmaxf(fmaxf(redm[H][0],redm[H][1]),fmaxf(redm[H][2],redm[H][3])),
                     fmaxf(fmaxf(redm[H][4],redm[H][5]),fmaxf(redm[H][6],redm[H][7])));
    float e = EXP2F((sc - bm) * L2E);
    float se = waveRedSum(e);
    if (lane == 0) reds[H][wq8] = se;
    __syncthreads();
    float bs = reds[H][0]+reds[H][1]+reds[H][2]+reds[H][3]
             + reds[H][4]+reds[H][5]+reds[H][6]+reds[H][7];
    float pv = e * RCPF(bs);
    pr[H][u] = pv;
    probs[((size_t)(b * TQ + qabs0 + H)) * TK + u] = pv;
  }
  __syncthreads();

  {
    const float* vcol = values + ((size_t)(b * TK) + 256 * H) * NN + u;
    const float4* p0 = (const float4*)(pr[0] + 256 * H);
    const float4* p1 = (const float4*)(pr[1] + 256 * H);
    float c0a=0.f, c0b=0.f, c1a=0.f, c1b=0.f;
    #pragma unroll 2
    for (int k = 0; k < 256; k += 8) {
      float v0 = vcol[(size_t)(k+0)*NN]; float v1 = vcol[(size_t)(k+1)*NN];
      float v2 = vcol[(size_t)(k+2)*NN]; float v3 = vcol[(size_t)(k+3)*NN];
      float v4 = vcol[(size_t)(k+4)*NN]; float v5 = vcol[(size_t)(k+5)*NN];
      float v6 = vcol[(size_t)(k+6)*NN]; float v7 = vcol[(size_t)(k+7)*NN];
      float4 pA = p0[k>>2], pB = p0[(k>>2)+1];
      float4 qA = p1[k>>2], qB = p1[(k>>2)+1];
      c0a = fmaf(pA.x,v0,c0a); c0a = fmaf(pA.y,v1,c0a);
      c0b = fmaf(pA.z,v2,c0b); c0b = fmaf(pA.w,v3,c0b);
      c0a = fmaf(pB.x,v4,c0a); c0a = fmaf(pB.y,v5,c0a);
      c0b = fmaf(pB.z,v6,c0b); c0b = fmaf(pB.w,v7,c0b);
      c1a = fmaf(qA.x,v0,c1a); c1a = fmaf(qA.y,v1,c1a);
      c1b = fmaf(qA.z,v2,c1b); c1b = fmaf(qA.w,v3,c1b);
      c1a = fmaf(qB.x,v4,c1a); c1a = fmaf(qB.y,v5,c1a);
      c1b = fmaf(qB.z,v6,c1b); c1b = fmaf(qB.w,v7,c1b);
    }
    part[H][0][u] = c0a + c0b; part[H][1][u] = c1a + c1b;
  }
  __syncthreads();
  ctx[H][u] = part[0][H][u] + part[1][H][u];
  __syncthreads();

  {
    const float4* wo = (const float4*)(W_out + (size_t)u * CATSZ + 512 * H);
    const float4* x4 = (H == 0) ? (const float4*)qv[0] : (const float4*)ctx[0];
    const float4* y4 = (H == 0) ? (const float4*)qv[1] : (const float4*)ctx[1];
    float o0=0.f, o0b=0.f, o1=0.f, o1b=0.f;
    #pragma unroll 2
    for (int c = 0; c < 32; ++c) {
      float4 wA=wo[4*c+0], wB=wo[4*c+1], wC=wo[4*c+2], wD=wo[4*c+3];
      float4 xA=x4[4*c+0], xB=x4[4*c+1], xC=x4[4*c+2], xD=x4[4*c+3];
      o0 = fma4(wA,xA,o0); o0b = fma4(wB,xB,o0b);
      o0 = fma4(wC,xC,o0); o0b = fma4(wD,xD,o0b);
      float4 yA=y4[4*c+0], yB=y4[4*c+1], yC=y4[4*c+2], yD=y4[4*c+3];
      o1 = fma4(wA,yA,o1); o1b = fma4(wB,yB,o1b);
      o1 = fma4(wC,yC,o1); o1b = fma4(wD,yD,o1b);
    }
    part[H][0][u] = o0 + o0b; part[H][1][u] = o1 + o1b;
  }
  __syncthreads();
  {
    float oo = part[0][H][u] + part[1][H][u] + b_out[u];
    out[((size_t)(b * TQ + qabs0 + H)) * OUTSZ + u] = fast_tanh(oo);
  }
}

extern "C" void kernel_launch(void* const* d_in, const int* in_sizes, int n_in,
                              void* d_out, int out_size, void* d_ws, size_t ws_size,
                              hipStream_t stream) {
  const float* query = (const float*)d_in[0];
  const float* keys  = (const float*)d_in[1];
  const float* vals  = (const float*)d_in[2];
  const float* W_q   = (const float*)d_in[3];
  const float* b_q   = (const float*)d_in[4];
  const float* w_att = (const float*)d_in[5];
  const float* b_att = (const float*)d_in[6];
  const float* W_out = (const float*)d_in[7];
  const float* b_out = (const float*)d_in[8];

  float* out   = (float*)d_out;
  float* probs = out + (size_t)BB * TQ * OUTSZ;

  if (ws_size >= (size_t)WS_HALVES * sizeof(_Float16)) {
    _Float16* ws = (_Float16*)d_ws;
    pack_kernel<<<dim3(3072), dim3(256), 0, stream>>>(query, keys, W_q, W_out,
                                                      vals, b_q, w_att, ws);
    attn_mid<<<dim3(BB * TQ / 2), dim3(1024), 0, stream>>>(ws, probs);
    out_kernel<<<dim3(256), dim3(1024), 0, stream>>>(b_out, ws, out);
  } else {
    attn_fallback<<<dim3(BB * TQ / 2), dim3(1024), 0, stream>>>(
        query, keys, vals, W_q, b_q, w_att, b_att, W_out, b_out, out, probs);
  }
}

// Round 3
// 115.609 us; speedup vs baseline: 1.1012x; 1.1012x over previous
//
#include <hip/hip_runtime.h>
#include <hip/hip_fp16.h>

// Shape: b=4, t_q=128, t_k=512, n=512, out=512. All fp32 in/out.
// Output: [out (4*128*512), probs (4*128*512)].
//
// Round-17: revert to round-14's fused 2-kernel structure (best measured,
// 115.8us; R15 split cost ~5us in gaps/round-trips, R16's raw-W_q attq fold
// was uncoalesced, +9us). ONE change on top of round-14:
//   Fuse the QUERY-half of the out-GEMM (W_out cols c<512, which depend only
//   on the staged query rows, not on context) into step-2's trans-bound loop.
//   Step 2 has ~3.4us of idle mem BW under its 6.8us trans floor (1 block/CU,
//   barrier-serialized phases, 64B/cy/CU L1 return BW); the extra 2 uint4
//   W_out loads + 16 fdot2 per iter ride in that shadow -> step 5 shrinks to
//   the ctx-half only. Predicted serial/CU: 21.8 -> ~18.4us.
//   New 32KB pt2 scratch holds the query-half partials (LDS 74KB, 1 blk/CU).

#define BB    4
#define TQ    128
#define TK    512
#define NN    512
#define OUTSZ 512
#define CATSZ 1024
#define K2E   2.8853900817779268f   // 2*log2(e)
#define L2E   1.4426950408889634f   // log2(e)
#define MAT   262144                // 512*512
// ws halves: keysE[0,4M) W_qP[4M,5M) W_outP[5M,7M) valuesP[7M,11M)
#define WS_HALVES (11 * MAT)

typedef __attribute__((ext_vector_type(4))) _Float16 half4;
typedef __attribute__((ext_vector_type(8))) _Float16 half8;
typedef __attribute__((ext_vector_type(2))) _Float16 h2;

#if __has_builtin(__builtin_amdgcn_exp2f)
#define EXP2F(x) __builtin_amdgcn_exp2f(x)
#else
#define EXP2F(x) exp2f(x)
#endif
#if __has_builtin(__builtin_amdgcn_rcpf)
#define RCPF(x) __builtin_amdgcn_rcpf(x)
#else
#define RCPF(x) (1.0f / (x))
#endif

__device__ __forceinline__ h2 u2h(unsigned int u) {
  union { unsigned int i; h2 h; } v; v.i = u; return v.h;
}
__device__ __forceinline__ half4 uu2h4(unsigned int a, unsigned int b) {
  union { uint2 u; half4 h; } c; c.u = make_uint2(a, b); return c.h;
}
#if __has_builtin(__builtin_amdgcn_fdot2)
__device__ __forceinline__ float FDOT2(h2 a, h2 b, float c) {
  return __builtin_amdgcn_fdot2(a, b, c, false);
}
#else
__device__ __forceinline__ float FDOT2(h2 a, h2 b, float c) {
  return fmaf((float)a.x, (float)b.x, fmaf((float)a.y, (float)b.y, c));
}
#endif

__device__ __forceinline__ float fast_tanh(float x) {
  float e = EXP2F(x * K2E);
  return fmaf(-2.0f, RCPF(e + 1.0f), 1.0f);
}
__device__ __forceinline__ float waveRedSum(float s) {
  #pragma unroll
  for (int m = 32; m >= 1; m >>= 1) s += __shfl_xor(s, m, 64);
  return s;
}
__device__ __forceinline__ float fma4(float4 w, float4 v, float acc) {
  acc = fmaf(w.x, v.x, acc); acc = fmaf(w.y, v.y, acc);
  acc = fmaf(w.z, v.z, acc); acc = fmaf(w.w, v.w, acc);
  return acc;
}
// score quad: s[i] += w * rcp(E_h[i]*A + 1)
__device__ __forceinline__ float4 scqh(float4 s, half4 E, float A, float w) {
  s.x = fmaf(w, RCPF(fmaf((float)E.x, A, 1.0f)), s.x);
  s.y = fmaf(w, RCPF(fmaf((float)E.y, A, 1.0f)), s.y);
  s.z = fmaf(w, RCPF(fmaf((float)E.z, A, 1.0f)), s.z);
  s.w = fmaf(w, RCPF(fmaf((float)E.w, A, 1.0f)), s.w);
  return s;
}
// paired-GEMM micro-op: 8 fdot2 for 4 outputs x 2 rows, one contraction pair
__device__ __forceinline__ void dotq(float4& r0, float4& r1, uint4 wp, unsigned int cpa, unsigned int cpb) {
  h2 c0 = u2h(cpa), c1 = u2h(cpb);
  r0.x = FDOT2(u2h(wp.x), c0, r0.x); r1.x = FDOT2(u2h(wp.x), c1, r1.x);
  r0.y = FDOT2(u2h(wp.y), c0, r0.y); r1.y = FDOT2(u2h(wp.y), c1, r1.y);
  r0.z = FDOT2(u2h(wp.z), c0, r0.z); r1.z = FDOT2(u2h(wp.z), c1, r1.z);
  r0.w = FDOT2(u2h(wp.w), c0, r0.w); r1.w = FDOT2(u2h(wp.w), c1, r1.w);
}

// ---------------- pack kernel (round-14, unchanged) --------------------------
__global__ __launch_bounds__(256)
void pack_kernel(const float* __restrict__ keys, const float* __restrict__ W_q,
                 const float* __restrict__ W_out, const float* __restrict__ values,
                 _Float16* __restrict__ ws)
{
  __shared__ float tile[32][33];
  const int idx = blockIdx.x;
  const int tx = threadIdx.x & 31, ty = threadIdx.x >> 5;   // 32x8

  if (idx >= 1792) {                      // valuesP: 1024 blocks, 2 k-rows each
    int r = idx - 1792;
    int b = r >> 8, k2 = r & 255;
    const float* r0 = values + ((size_t)b * 512 + 2 * k2) * 512;
    const float* r1 = r0 + 512;
    int n0 = threadIdx.x * 2;
    float2 a = *(const float2*)(r0 + n0);
    float2 c = *(const float2*)(r1 + n0);
    _Float16* dst = ws + (size_t)7 * MAT + (size_t)b * MAT + k2 * 1024 + n0 * 2;
    half4 h = {(_Float16)a.x, (_Float16)c.x, (_Float16)a.y, (_Float16)c.y};
    *(half4*)dst = h;
    return;
  }

  if (idx < 1024) {                       // keysE: transpose + exp2
    int b = idx >> 8, r = idx & 255;
    int by = r >> 4, bx = r & 15;
    const float* src = keys + (size_t)b * MAT;
    _Float16* dst = ws + (size_t)b * MAT;
    #pragma unroll
    for (int i = 0; i < 32; i += 8)
      tile[ty + i][tx] = src[(size_t)(by * 32 + ty + i) * 512 + bx * 32 + tx] * K2E;
    __syncthreads();
    #pragma unroll
    for (int i = 0; i < 32; i += 8)
      dst[(size_t)(bx * 32 + ty + i) * 512 + by * 32 + tx] = (_Float16)EXP2F(tile[tx][ty + i]);
    return;
  }

  const float* src; _Float16* dst; int N; int by, bx;
  if (idx < 1280) {                       // W_qP
    int r = idx - 1024; by = r >> 4; bx = r & 15;
    src = W_q; dst = ws + (size_t)4 * MAT; N = 512;
  } else {                                // W_outP
    int r = idx - 1280; by = r >> 5; bx = r & 31;
    src = W_out; dst = ws + (size_t)5 * MAT; N = 1024;
  }
  #pragma unroll
  for (int i = 0; i < 32; i += 8)
    tile[ty + i][tx] = src[(size_t)(by * 32 + ty + i) * N + bx * 32 + tx];
  __syncthreads();
  #pragma unroll
  for (int i = 0; i < 32; i += 8) {
    int d = bx * 32 + ty + i;             // contraction index (d or c)
    int o = by * 32 + tx;                 // output index (n or o)
    dst[(size_t)(d >> 1) * 1024 + o * 2 + (d & 1)] = (_Float16)tile[tx][ty + i];
  }
}

// ---------------- main kernel ------------------------------------------------
__global__ __launch_bounds__(1024, 4)
void attn_main(const float* __restrict__ query,
               const float* __restrict__ b_q, const float* __restrict__ w_att,
               const float* __restrict__ b_att, const float* __restrict__ b_out,
               const _Float16* __restrict__ ws,
               float* __restrict__ out, float* __restrict__ probs)
{
  // catH[(c>>1)*4 + row*2 + (c&1)]: c in [0,512) query, [512,1024) ctx
  __shared__ __align__(16) _Float16 catH[2048];   // 4 KB
  __shared__ __align__(16) _Float16 pawF[NN * 4]; // {A0,A1,w,pad} per n, 4 KB
  __shared__ __align__(16) _Float16 prH[1024];    // probs pairs, 2 KB
  __shared__ __align__(16) float  pt[8][2][NN];   // partial scratch 32 KB
  __shared__ __align__(16) float  pt2[8][2][NN];  // out query-half partials 32 KB
  __shared__ float reds2[2][8];

  // fp16 view of the same scratch for step 2: ptH[qh][G16][k]  (k-contiguous)
  _Float16* ptH = (_Float16*)pt;                  // 2*16*512 halves = 32 KB

  const _Float16* wsKeys  = ws;
  const _Float16* wsWqP   = ws + (size_t)4 * MAT;
  const _Float16* wsWoutP = ws + (size_t)5 * MAT;
  const _Float16* wsValP  = ws + (size_t)7 * MAT;

  const int t    = threadIdx.x;        // 0..1023
  const int qh   = t >> 9;             // combine-phase q row (0/1)
  const int u    = t & 511;            // combine-phase index
  const int G    = t >> 7;             // contraction range 0..7 (wave-uniform)
  const int v    = t & 127;            // output quad index (4v..4v+3)
  const int G16  = t >> 6;             // step-2 contraction range 0..15 (=wave)
  const int v6   = t & 63;             // step-2 k-oct index (8*v6 .. +8) (=lane)
  const int wave = t >> 6, lane = t & 63, wq8 = wave & 7;

  const int p  = blockIdx.x;                 // 0..255 (XCD swizzle)
  const int b  = (p & 7) >> 1;
  const int qg = ((p >> 3) << 1) | (p & 1);
  const int qabs0 = qg * 2;

  // ---- stage: query rows -> catH (fp16 pairs) ----
  if (qh == 0) {
    float q0 = query[((size_t)(b * TQ + qabs0 + 0)) * NN + u];
    float q1 = query[((size_t)(b * TQ + qabs0 + 1)) * NN + u];
    catH[(u >> 1) * 4 + (u & 1)]     = (_Float16)q0;
    catH[(u >> 1) * 4 + 2 + (u & 1)] = (_Float16)q1;
  }
  __syncthreads();

  // ---- step 1: att_q partials via fdot2.  Thread (G,v): n quad 4v, d2 in [32G,+32).
  {
    const _Float16* wq = wsWqP + 8 * v;
    float4 a0 = {0,0,0,0}, a1 = {0,0,0,0};
    #pragma unroll 2
    for (int j2 = 0; j2 < 32; j2 += 2) {
      int d2 = 32 * G + j2;
      uint4 wp0 = *(const uint4*)(wq + (size_t)d2 * 1024);
      uint4 wp1 = *(const uint4*)(wq + (size_t)(d2 + 1) * 1024);
      uint4 cp2 = *(const uint4*)(&catH[d2 * 4]);
      dotq(a0, a1, wp0, cp2.x, cp2.y);
      dotq(a0, a1, wp1, cp2.z, cp2.w);
    }
    *(float4*)(&pt[G][0][4 * v]) = a0;
    *(float4*)(&pt[G][1][4 * v]) = a1;
  }
  __syncthreads();
  // combine: thread (qh,u): A = exp2(K2E * att_q); build pawF (fp16 quads)
  {
    float s = pt[0][qh][u] + pt[1][qh][u] + pt[2][qh][u] + pt[3][qh][u]
            + pt[4][qh][u] + pt[5][qh][u] + pt[6][qh][u] + pt[7][qh][u];
    float A = EXP2F(K2E * (s + b_q[u]));
    if (qh == 0) {
      pawF[u * 4 + 0] = (_Float16)A;
      pawF[u * 4 + 2] = (_Float16)w_att[u];
      pawF[u * 4 + 3] = (_Float16)0.f;
    } else {
      pawF[u * 4 + 1] = (_Float16)A;
    }
  }
  __syncthreads();

  // ---- step 2 (hot, fused): score partials + out-GEMM query half.
  //      Score: thread (G16,v6): k in [8v6,+8), n in [32*G16,+32).
  //      Fused out-q: thread (G,v): o quad 4v, c2 in [32G,+32)  (c<512: query).
  //      The W_out loads+fdot2 ride in step-2's trans-pipe shadow.
  {
    const _Float16* ke = wsKeys + (size_t)b * MAT + 8 * v6;
    const _Float16* wo = wsWoutP + 8 * v;
    float4 s0a = {0,0,0,0}, s0b = {0,0,0,0};
    float4 s1a = {0,0,0,0}, s1b = {0,0,0,0};
    float4 o0 = {0,0,0,0}, o1 = {0,0,0,0};
    #pragma unroll 2
    for (int j = 0; j < 32; j += 2) {
      int n = 32 * G16 + j;
      uint4 Eu0 = *(const uint4*)(ke + (size_t)n * 512);
      uint4 Eu1 = *(const uint4*)(ke + (size_t)(n + 1) * 512);
      uint4 pw  = *(const uint4*)(&pawF[n * 4]);   // {A0,A1,w,pad}x2
      h2 Aab = u2h(pw.x);  float w0f = (float)u2h(pw.y).x;
      h2 Acd = u2h(pw.z);  float w1f = (float)u2h(pw.w).x;
      float A0n = (float)Aab.x, A1n = (float)Aab.y;
      float A0m = (float)Acd.x, A1m = (float)Acd.y;
      half4 E0lo = uu2h4(Eu0.x, Eu0.y), E0hi = uu2h4(Eu0.z, Eu0.w);
      half4 E1lo = uu2h4(Eu1.x, Eu1.y), E1hi = uu2h4(Eu1.z, Eu1.w);
      s0a = scqh(s0a, E0lo, A0n, w0f);
      s0b = scqh(s0b, E0hi, A0n, w0f);
      s1a = scqh(s1a, E0lo, A1n, w0f);
      s1b = scqh(s1b, E0hi, A1n, w0f);
      s0a = scqh(s0a, E1lo, A0m, w1f);
      s0b = scqh(s0b, E1hi, A0m, w1f);
      s1a = scqh(s1a, E1lo, A1m, w1f);
      s1b = scqh(s1b, E1hi, A1m, w1f);
      // fused out-GEMM (query half): c2 = 32G+j, 32G+j+1
      int c2 = 32 * G + j;
      uint4 wp0 = *(const uint4*)(wo + (size_t)c2 * 1024);
      uint4 wp1 = *(const uint4*)(wo + (size_t)(c2 + 1) * 1024);
      uint4 cq2 = *(const uint4*)(&catH[c2 * 4]);
      dotq(o0, o1, wp0, cq2.x, cq2.y);
      dotq(o0, o1, wp1, cq2.z, cq2.w);
    }
    // conflict-free stores: ptH[qh][G16][8*v6..+8] = one half8 (b128) each
    half8 w0 = {(_Float16)s0a.x, (_Float16)s0a.y, (_Float16)s0a.z, (_Float16)s0a.w,
                (_Float16)s0b.x, (_Float16)s0b.y, (_Float16)s0b.z, (_Float16)s0b.w};
    half8 w1 = {(_Float16)s1a.x, (_Float16)s1a.y, (_Float16)s1a.z, (_Float16)s1a.w,
                (_Float16)s1b.x, (_Float16)s1b.y, (_Float16)s1b.z, (_Float16)s1b.w};
    *(half8*)(ptH + (size_t)G16 * 512 + 8 * v6)        = w0;
    *(half8*)(ptH + 8192 + (size_t)G16 * 512 + 8 * v6) = w1;
    *(float4*)(&pt2[G][0][4 * v]) = o0;
    *(float4*)(&pt2[G][1][4 * v]) = o1;
  }
  __syncthreads();

  // ---- softmax (no max-subtraction; batt+sumW cancels): thread (qh,u), k=u.
  {
    const _Float16* pp = ptH + qh * 8192 + u;   // stride 512 halves over G16
    float s = 0.f;
    #pragma unroll
    for (int g = 0; g < 16; ++g)
      s += (float)pp[g * 512];
    float e = EXP2F(-K2E * s);           // softmax weight (constants cancel)
    float se = waveRedSum(e);
    if (lane == 0) reds2[qh][wq8] = se;
    __syncthreads();
    float bs = reds2[qh][0]+reds2[qh][1]+reds2[qh][2]+reds2[qh][3]
             + reds2[qh][4]+reds2[qh][5]+reds2[qh][6]+reds2[qh][7];
    float pv = e * RCPF(bs);
    prH[(u >> 1) * 4 + qh * 2 + (u & 1)] = (_Float16)pv;
    probs[((size_t)(b * TQ + qabs0 + qh)) * TK + u] = pv;
  }
  __syncthreads();

  // ---- step 4: context partials via fdot2.  Thread (G,v): n quad 4v, k2 in [32G,+32).
  {
    const _Float16* vp = wsValP + (size_t)b * MAT + 8 * v;
    float4 c0 = {0,0,0,0}, c1 = {0,0,0,0};
    #pragma unroll 2
    for (int j2 = 0; j2 < 32; j2 += 2) {
      int k2 = 32 * G + j2;
      uint4 vk0 = *(const uint4*)(vp + (size_t)k2 * 1024);
      uint4 vk1 = *(const uint4*)(vp + (size_t)(k2 + 1) * 1024);
      uint4 pp2 = *(const uint4*)(&prH[k2 * 4]);
      dotq(c0, c1, vk0, pp2.x, pp2.y);
      dotq(c0, c1, vk1, pp2.z, pp2.w);
    }
    *(float4*)(&pt[G][0][4 * v]) = c0;
    *(float4*)(&pt[G][1][4 * v]) = c1;
  }
  __syncthreads();
  {
    float s = pt[0][qh][u] + pt[1][qh][u] + pt[2][qh][u] + pt[3][qh][u]
            + pt[4][qh][u] + pt[5][qh][u] + pt[6][qh][u] + pt[7][qh][u];
    catH[(256 + (u >> 1)) * 4 + qh * 2 + (u & 1)] = (_Float16)s;
  }
  __syncthreads();

  // ---- step 5 (ctx half only): thread (G,v): o quad 4v, c2 in [256+32G,+32).
  {
    const _Float16* wo = wsWoutP + 8 * v;
    float4 o0 = {0,0,0,0}, o1 = {0,0,0,0};
    #pragma unroll 2
    for (int j2 = 0; j2 < 32; j2 += 2) {
      int c2 = 256 + 32 * G + j2;
      uint4 wp0 = *(const uint4*)(wo + (size_t)c2 * 1024);
      uint4 wp1 = *(const uint4*)(wo + (size_t)(c2 + 1) * 1024);
      uint4 cp2 = *(const uint4*)(&catH[c2 * 4]);
      dotq(o0, o1, wp0, cp2.x, cp2.y);
      dotq(o0, o1, wp1, cp2.z, cp2.w);
    }
    *(float4*)(&pt[G][0][4 * v]) = o0;
    *(float4*)(&pt[G][1][4 * v]) = o1;
  }
  __syncthreads();
  {
    float sq = pt2[0][qh][u] + pt2[1][qh][u] + pt2[2][qh][u] + pt2[3][qh][u]
             + pt2[4][qh][u] + pt2[5][qh][u] + pt2[6][qh][u] + pt2[7][qh][u];
    float sc = pt[0][qh][u] + pt[1][qh][u] + pt[2][qh][u] + pt[3][qh][u]
             + pt[4][qh][u] + pt[5][qh][u] + pt[6][qh][u] + pt[7][qh][u];
    float oo = sq + sc + b_out[u];
    out[((size_t)(b * TQ + qabs0 + qh)) * OUTSZ + u] = fast_tanh(oo);
  }
}

// ---------------- round-6-style fallback (ws too small) ----------------------
__device__ __forceinline__ float sc4f(float4 w, float4 k, float4 a, float acc) {
  acc = fmaf(w.x, RCPF(EXP2F(fmaf(k.x, K2E, a.x)) + 1.0f), acc);
  acc = fmaf(w.y, RCPF(EXP2F(fmaf(k.y, K2E, a.y)) + 1.0f), acc);
  acc = fmaf(w.z, RCPF(EXP2F(fmaf(k.z, K2E, a.z)) + 1.0f), acc);
  acc = fmaf(w.w, RCPF(EXP2F(fmaf(k.w, K2E, a.w)) + 1.0f), acc);
  return acc;
}

__global__ __launch_bounds__(1024, 4)
void attn_fallback(const float* __restrict__ query, const float* __restrict__ keys,
                   const float* __restrict__ values, const float* __restrict__ W_q,
                   const float* __restrict__ b_q, const float* __restrict__ w_att,
                   const float* __restrict__ b_att, const float* __restrict__ W_out,
                   const float* __restrict__ b_out,
                   float* __restrict__ out, float* __restrict__ probs)
{
  __shared__ __align__(16) float qv[2][NN];
  __shared__ __align__(16) float aqc[2][NN];
  __shared__ __align__(16) float wv[NN];
  __shared__ __align__(16) float pr[2][TK];
  __shared__ __align__(16) float ctx[2][NN];
  __shared__ __align__(16) float part[2][2][NN];
  __shared__ float redm[2][8], reds[2][8], redw[8];

  const int t = threadIdx.x, H = t >> 9, u = t & 511;
  const int wave = t >> 6, lane = t & 63, wq8 = wave & 7;
  const int p = blockIdx.x, b = (p & 7) >> 1;
  const int qg = ((p >> 3) << 1) | (p & 1), qabs0 = qg * 2;
  const float batt = b_att[0];

  if (H == 0) wv[u] = w_att[u];
  qv[H][u] = query[((size_t)(b * TQ + qabs0 + H)) * NN + u];
  __syncthreads();
  if (H == 0) {
    float wp = waveRedSum(wv[u]);
    if (lane == 0) redw[wq8] = wp;
  }
  __syncthreads();
  const float sumW = redw[0]+redw[1]+redw[2]+redw[3]+redw[4]+redw[5]+redw[6]+redw[7];

  {
    const float4* wq4 = (const float4*)(W_q + (size_t)u * NN + 256 * H);
    const float4* x4  = (const float4*)(qv[0] + 256 * H);
    const float4* y4  = (const float4*)(qv[1] + 256 * H);
    float a0=0.f, a0b=0.f, a1=0.f, a1b=0.f;
    #pragma unroll 2
    for (int c = 0; c < 16; ++c) {
      float4 wA=wq4[4*c+0], wB=wq4[4*c+1], wC=wq4[4*c+2], wD=wq4[4*c+3];
      float4 xA=x4[4*c+0], xB=x4[4*c+1], xC=x4[4*c+2], xD=x4[4*c+3];
      a0 = fma4(wA,xA,a0); a0b = fma4(wB,xB,a0b);
      a0 = fma4(wC,xC,a0); a0b = fma4(wD,xD,a0b);
      float4 yA=y4[4*c+0], yB=y4[4*c+1], yC=y4[4*c+2], yD=y4[4*c+3];
      a1 = fma4(wA,yA,a1); a1b = fma4(wB,yB,a1b);
      a1 = fma4(wC,yC,a1); a1b = fma4(wD,yD,a1b);
    }
    part[H][0][u] = a0 + a0b; part[H][1][u] = a1 + a1b;
  }
  __syncthreads();
  aqc[H][u] = (part[0][H][u] + part[1][H][u] + b_q[u]) * K2E;
  __syncthreads();

  {
    const float4* kr  = (const float4*)(keys + ((size_t)(b * TK) + u) * NN + 256 * H);
    const float4* a0p = (const float4*)(aqc[0] + 256 * H);
    const float4* a1p = (const float4*)(aqc[1] + 256 * H);
    const float4* w4  = (const float4*)(wv + 256 * H);
    float s0 = 0.f, s1 = 0.f;
    #pragma unroll 2
    for (int c = 0; c < 16; ++c) {
      float4 kA=kr[4*c+0], kB=kr[4*c+1], kC=kr[4*c+2], kD=kr[4*c+3];
      float4 wA=w4[4*c+0], wB=w4[4*c+1], wC=w4[4*c+2], wD=w4[4*c+3];
      float4 aA=a0p[4*c+0], aB=a0p[4*c+1], aC=a0p[4*c+2], aD=a0p[4*c+3];
      s0 = sc4f(wA,kA,aA,s0); s0 = sc4f(wB,kB,aB,s0);
      s0 = sc4f(wC,kC,aC,s0); s0 = sc4f(wD,kD,aD,s0);
      float4 bA=a1p[4*c+0], bB=a1p[4*c+1], bC=a1p[4*c+2], bD=a1p[4*c+3];
      s1 = sc4f(wA,kA,bA,s1); s1 = sc4f(wB,kB,bB,s1);
      s1 = sc4f(wC,kC,bC,s1); s1 = sc4f(wD,kD,bD,s1);
    }
    part[H][0][u] = s0; part[H][1][u] = s1;
  }
  __syncthreads();

  {
    float sc = batt + sumW - 2.0f * (part[0][H][u] + part[1][H][u]);
    float m = sc;
    #pragma unroll
    for (int mm = 32; mm >= 1; mm >>= 1) m = fmaxf(m, __shfl_xor(m, mm, 64));
    if (lane == 0) redm[H][wq8] = m;
    __syncthreads();
    float bm = fmaxf(fmaxf(fmaxf(redm[H][0],redm[H][1]),fmaxf(redm[H][2],redm[H][3])),
                     fmaxf(fmaxf(redm[H][4],redm[H][5]),fmaxf(redm[H][6],redm[H][7])));
    float e = EXP2F((sc - bm) * L2E);
    float se = waveRedSum(e);
    if (lane == 0) reds[H][wq8] = se;
    __syncthreads();
    float bs = reds[H][0]+reds[H][1]+reds[H][2]+reds[H][3]
             + reds[H][4]+reds[H][5]+reds[H][6]+reds[H][7];
    float pv = e * RCPF(bs);
    pr[H][u] = pv;
    probs[((size_t)(b * TQ + qabs0 + H)) * TK + u] = pv;
  }
  __syncthreads();

  {
    const float* vcol = values + ((size_t)(b * TK) + 256 * H) * NN + u;
    const float4* p0 = (const float4*)(pr[0] + 256 * H);
    const float4* p1 = (const float4*)(pr[1] + 256 * H);
    float c0a=0.f, c0b=0.f, c1a=0.f, c1b=0.f;
    #pragma unroll 2
    for (int k = 0; k < 256; k += 8) {
      float v0 = vcol[(size_t)(k+0)*NN]; float v1 = vcol[(size_t)(k+1)*NN];
      float v2 = vcol[(size_t)(k+2)*NN]; float v3 = vcol[(size_t)(k+3)*NN];
      float v4 = vcol[(size_t)(k+4)*NN]; float v5 = vcol[(size_t)(k+5)*NN];
      float v6 = vcol[(size_t)(k+6)*NN]; float v7 = vcol[(size_t)(k+7)*NN];
      float4 pA = p0[k>>2], pB = p0[(k>>2)+1];
      float4 qA = p1[k>>2], qB = p1[(k>>2)+1];
      c0a = fmaf(pA.x,v0,c0a); c0a = fmaf(pA.y,v1,c0a);
      c0b = fmaf(pA.z,v2,c0b); c0b = fmaf(pA.w,v3,c0b);
      c0a = fmaf(pB.x,v4,c0a); c0a = fmaf(pB.y,v5,c0a);
      c0b = fmaf(pB.z,v6,c0b); c0b = fmaf(pB.w,v7,c0b);
      c1a = fmaf(qA.x,v0,c1a); c1a = fmaf(qA.y,v1,c1a);
      c1b = fmaf(qA.z,v2,c1b); c1b = fmaf(qA.w,v3,c1b);
      c1a = fmaf(qB.x,v4,c1a); c1a = fmaf(qB.y,v5,c1a);
      c1b = fmaf(qB.z,v6,c1b); c1b = fmaf(qB.w,v7,c1b);
    }
    part[H][0][u] = c0a + c0b; part[H][1][u] = c1a + c1b;
  }
  __syncthreads();
  ctx[H][u] = part[0][H][u] + part[1][H][u];
  __syncthreads();

  {
    const float4* wo = (const float4*)(W_out + (size_t)u * CATSZ + 512 * H);
    const float4* x4 = (H == 0) ? (const float4*)qv[0] : (const float4*)ctx[0];
    const float4* y4 = (H == 0) ? (const float4*)qv[1] : (const float4*)ctx[1];
    float o0=0.f, o0b=0.f, o1=0.f, o1b=0.f;
    #pragma unroll 2
    for (int c = 0; c < 32; ++c) {
      float4 wA=wo[4*c+0], wB=wo[4*c+1], wC=wo[4*c+2], wD=wo[4*c+3];
      float4 xA=x4[4*c+0], xB=x4[4*c+1], xC=x4[4*c+2], xD=x4[4*c+3];
      o0 = fma4(wA,xA,o0); o0b = fma4(wB,xB,o0b);
      o0 = fma4(wC,xC,o0); o0b = fma4(wD,xD,o0b);
      float4 yA=y4[4*c+0], yB=y4[4*c+1], yC=y4[4*c+2], yD=y4[4*c+3];
      o1 = fma4(wA,yA,o1); o1b = fma4(wB,yB,o1b);
      o1 = fma4(wC,yC,o1); o1b = fma4(wD,yD,o1b);
    }
    part[H][0][u] = o0 + o0b; part[H][1][u] = o1 + o1b;
  }
  __syncthreads();
  {
    float oo = part[0][H][u] + part[1][H][u] + b_out[u];
    out[((size_t)(b * TQ + qabs0 + H)) * OUTSZ + u] = fast_tanh(oo);
  }
}

extern "C" void kernel_launch(void* const* d_in, const int* in_sizes, int n_in,
                              void* d_out, int out_size, void* d_ws, size_t ws_size,
                              hipStream_t stream) {
  const float* query = (const float*)d_in[0];
  const float* keys  = (const float*)d_in[1];
  const float* vals  = (const float*)d_in[2];
  const float* W_q   = (const float*)d_in[3];
  const float* b_q   = (const float*)d_in[4];
  const float* w_att = (const float*)d_in[5];
  const float* b_att = (const float*)d_in[6];
  const float* W_out = (const float*)d_in[7];
  const float* b_out = (const float*)d_in[8];

  float* out   = (float*)d_out;
  float* probs = out + (size_t)BB * TQ * OUTSZ;

  if (ws_size >= (size_t)WS_HALVES * sizeof(_Float16)) {
    _Float16* ws = (_Float16*)d_ws;
    pack_kernel<<<dim3(2816), dim3(256), 0, stream>>>(keys, W_q, W_out, vals, ws);
    attn_main<<<dim3(BB * TQ / 2), dim3(1024), 0, stream>>>(
        query, b_q, w_att, b_att, b_out, ws, out, probs);
  } else {
    attn_fallback<<<dim3(BB * TQ / 2), dim3(1024), 0, stream>>>(
        query, keys, vals, W_q, b_q, w_att, b_att, W_out, b_out, out, probs);
  }
}

// Round 4
// 113.037 us; speedup vs baseline: 1.1262x; 1.0228x over previous
//
#include <hip/hip_runtime.h>
#include <hip/hip_fp16.h>

// Shape: b=4, t_q=128, t_k=512, n=512, out=512. All fp32 in/out.
// Output: [out (4*128*512), probs (4*128*512)].
//
// Round-18 (on round-17): halve the trans-pipe cost of step 2.
//  R15/R17 nulls proved the phases are NOT byte-bound: moving 0.5-1.5 MB
//  between phases / kernels changed nothing. Remaining serial floor = the
//  rcp stream: 2 rcp per (k,n,row) = 524k/block, quarter-rate. Pair across
//  adjacent n (same k, row):  w0/a + w1/b = (w0*b + w1*a)*rcp(a*b)
//  -> 6 VALU + 1 trans per 2 elements (was 4 VALU + 2 trans). Per-k score
//  partials preserved (pairing is along the n reduction axis); softmax,
//  layouts, and all other phases byte-identical to round-17.
//  Range-safe: a,b in [1,1e9] -> a*b <= 1e18 < fp32 max; same absmax.

#define BB    4
#define TQ    128
#define TK    512
#define NN    512
#define OUTSZ 512
#define CATSZ 1024
#define K2E   2.8853900817779268f   // 2*log2(e)
#define L2E   1.4426950408889634f   // log2(e)
#define MAT   262144                // 512*512
// ws halves: keysE[0,4M) W_qP[4M,5M) W_outP[5M,7M) valuesP[7M,11M)
#define WS_HALVES (11 * MAT)

typedef __attribute__((ext_vector_type(4))) _Float16 half4;
typedef __attribute__((ext_vector_type(8))) _Float16 half8;
typedef __attribute__((ext_vector_type(2))) _Float16 h2;

#if __has_builtin(__builtin_amdgcn_exp2f)
#define EXP2F(x) __builtin_amdgcn_exp2f(x)
#else
#define EXP2F(x) exp2f(x)
#endif
#if __has_builtin(__builtin_amdgcn_rcpf)
#define RCPF(x) __builtin_amdgcn_rcpf(x)
#else
#define RCPF(x) (1.0f / (x))
#endif

__device__ __forceinline__ h2 u2h(unsigned int u) {
  union { unsigned int i; h2 h; } v; v.i = u; return v.h;
}
__device__ __forceinline__ half4 uu2h4(unsigned int a, unsigned int b) {
  union { uint2 u; half4 h; } c; c.u = make_uint2(a, b); return c.h;
}
#if __has_builtin(__builtin_amdgcn_fdot2)
__device__ __forceinline__ float FDOT2(h2 a, h2 b, float c) {
  return __builtin_amdgcn_fdot2(a, b, c, false);
}
#else
__device__ __forceinline__ float FDOT2(h2 a, h2 b, float c) {
  return fmaf((float)a.x, (float)b.x, fmaf((float)a.y, (float)b.y, c));
}
#endif

__device__ __forceinline__ float fast_tanh(float x) {
  float e = EXP2F(x * K2E);
  return fmaf(-2.0f, RCPF(e + 1.0f), 1.0f);
}
__device__ __forceinline__ float waveRedSum(float s) {
  #pragma unroll
  for (int m = 32; m >= 1; m >>= 1) s += __shfl_xor(s, m, 64);
  return s;
}
__device__ __forceinline__ float fma4(float4 w, float4 v, float acc) {
  acc = fmaf(w.x, v.x, acc); acc = fmaf(w.y, v.y, acc);
  acc = fmaf(w.z, v.z, acc); acc = fmaf(w.w, v.w, acc);
  return acc;
}
// paired score quad: s[i] += wa/(Ea[i]*Aa+1) + wb/(Eb[i]*Ab+1)
//                  = (wa*b + wb*a) * rcp(a*b)   -- 1 trans per 2 elements
__device__ __forceinline__ float4 scqp(float4 s, half4 Ea, half4 Eb,
                                       float Aa, float Ab, float wa, float wb) {
  {
    float a = fmaf((float)Ea.x, Aa, 1.0f), b = fmaf((float)Eb.x, Ab, 1.0f);
    s.x = fmaf(fmaf(wa, b, wb * a), RCPF(a * b), s.x);
  }
  {
    float a = fmaf((float)Ea.y, Aa, 1.0f), b = fmaf((float)Eb.y, Ab, 1.0f);
    s.y = fmaf(fmaf(wa, b, wb * a), RCPF(a * b), s.y);
  }
  {
    float a = fmaf((float)Ea.z, Aa, 1.0f), b = fmaf((float)Eb.z, Ab, 1.0f);
    s.z = fmaf(fmaf(wa, b, wb * a), RCPF(a * b), s.z);
  }
  {
    float a = fmaf((float)Ea.w, Aa, 1.0f), b = fmaf((float)Eb.w, Ab, 1.0f);
    s.w = fmaf(fmaf(wa, b, wb * a), RCPF(a * b), s.w);
  }
  return s;
}
// paired-GEMM micro-op: 8 fdot2 for 4 outputs x 2 rows, one contraction pair
__device__ __forceinline__ void dotq(float4& r0, float4& r1, uint4 wp, unsigned int cpa, unsigned int cpb) {
  h2 c0 = u2h(cpa), c1 = u2h(cpb);
  r0.x = FDOT2(u2h(wp.x), c0, r0.x); r1.x = FDOT2(u2h(wp.x), c1, r1.x);
  r0.y = FDOT2(u2h(wp.y), c0, r0.y); r1.y = FDOT2(u2h(wp.y), c1, r1.y);
  r0.z = FDOT2(u2h(wp.z), c0, r0.z); r1.z = FDOT2(u2h(wp.z), c1, r1.z);
  r0.w = FDOT2(u2h(wp.w), c0, r0.w); r1.w = FDOT2(u2h(wp.w), c1, r1.w);
}

// ---------------- pack kernel (round-14, unchanged) --------------------------
__global__ __launch_bounds__(256)
void pack_kernel(const float* __restrict__ keys, const float* __restrict__ W_q,
                 const float* __restrict__ W_out, const float* __restrict__ values,
                 _Float16* __restrict__ ws)
{
  __shared__ float tile[32][33];
  const int idx = blockIdx.x;
  const int tx = threadIdx.x & 31, ty = threadIdx.x >> 5;   // 32x8

  if (idx >= 1792) {                      // valuesP: 1024 blocks, 2 k-rows each
    int r = idx - 1792;
    int b = r >> 8, k2 = r & 255;
    const float* r0 = values + ((size_t)b * 512 + 2 * k2) * 512;
    const float* r1 = r0 + 512;
    int n0 = threadIdx.x * 2;
    float2 a = *(const float2*)(r0 + n0);
    float2 c = *(const float2*)(r1 + n0);
    _Float16* dst = ws + (size_t)7 * MAT + (size_t)b * MAT + k2 * 1024 + n0 * 2;
    half4 h = {(_Float16)a.x, (_Float16)c.x, (_Float16)a.y, (_Float16)c.y};
    *(half4*)dst = h;
    return;
  }

  if (idx < 1024) {                       // keysE: transpose + exp2
    int b = idx >> 8, r = idx & 255;
    int by = r >> 4, bx = r & 15;
    const float* src = keys + (size_t)b * MAT;
    _Float16* dst = ws + (size_t)b * MAT;
    #pragma unroll
    for (int i = 0; i < 32; i += 8)
      tile[ty + i][tx] = src[(size_t)(by * 32 + ty + i) * 512 + bx * 32 + tx] * K2E;
    __syncthreads();
    #pragma unroll
    for (int i = 0; i < 32; i += 8)
      dst[(size_t)(bx * 32 + ty + i) * 512 + by * 32 + tx] = (_Float16)EXP2F(tile[tx][ty + i]);
    return;
  }

  const float* src; _Float16* dst; int N; int by, bx;
  if (idx < 1280) {                       // W_qP
    int r = idx - 1024; by = r >> 4; bx = r & 15;
    src = W_q; dst = ws + (size_t)4 * MAT; N = 512;
  } else {                                // W_outP
    int r = idx - 1280; by = r >> 5; bx = r & 31;
    src = W_out; dst = ws + (size_t)5 * MAT; N = 1024;
  }
  #pragma unroll
  for (int i = 0; i < 32; i += 8)
    tile[ty + i][tx] = src[(size_t)(by * 32 + ty + i) * N + bx * 32 + tx];
  __syncthreads();
  #pragma unroll
  for (int i = 0; i < 32; i += 8) {
    int d = bx * 32 + ty + i;             // contraction index (d or c)
    int o = by * 32 + tx;                 // output index (n or o)
    dst[(size_t)(d >> 1) * 1024 + o * 2 + (d & 1)] = (_Float16)tile[tx][ty + i];
  }
}

// ---------------- main kernel ------------------------------------------------
__global__ __launch_bounds__(1024, 4)
void attn_main(const float* __restrict__ query,
               const float* __restrict__ b_q, const float* __restrict__ w_att,
               const float* __restrict__ b_att, const float* __restrict__ b_out,
               const _Float16* __restrict__ ws,
               float* __restrict__ out, float* __restrict__ probs)
{
  // catH[(c>>1)*4 + row*2 + (c&1)]: c in [0,512) query, [512,1024) ctx
  __shared__ __align__(16) _Float16 catH[2048];   // 4 KB
  __shared__ __align__(16) _Float16 pawF[NN * 4]; // {A0,A1,w,pad} per n, 4 KB
  __shared__ __align__(16) _Float16 prH[1024];    // probs pairs, 2 KB
  __shared__ __align__(16) float  pt[8][2][NN];   // partial scratch 32 KB
  __shared__ __align__(16) float  pt2[8][2][NN];  // out query-half partials 32 KB
  __shared__ float reds2[2][8];

  // fp16 view of the same scratch for step 2: ptH[qh][G16][k]  (k-contiguous)
  _Float16* ptH = (_Float16*)pt;                  // 2*16*512 halves = 32 KB

  const _Float16* wsKeys  = ws;
  const _Float16* wsWqP   = ws + (size_t)4 * MAT;
  const _Float16* wsWoutP = ws + (size_t)5 * MAT;
  const _Float16* wsValP  = ws + (size_t)7 * MAT;

  const int t    = threadIdx.x;        // 0..1023
  const int qh   = t >> 9;             // combine-phase q row (0/1)
  const int u    = t & 511;            // combine-phase index
  const int G    = t >> 7;             // contraction range 0..7 (wave-uniform)
  const int v    = t & 127;            // output quad index (4v..4v+3)
  const int G16  = t >> 6;             // step-2 contraction range 0..15 (=wave)
  const int v6   = t & 63;             // step-2 k-oct index (8*v6 .. +8) (=lane)
  const int wave = t >> 6, lane = t & 63, wq8 = wave & 7;

  const int p  = blockIdx.x;                 // 0..255 (XCD swizzle)
  const int b  = (p & 7) >> 1;
  const int qg = ((p >> 3) << 1) | (p & 1);
  const int qabs0 = qg * 2;

  // ---- stage: query rows -> catH (fp16 pairs) ----
  if (qh == 0) {
    float q0 = query[((size_t)(b * TQ + qabs0 + 0)) * NN + u];
    float q1 = query[((size_t)(b * TQ + qabs0 + 1)) * NN + u];
    catH[(u >> 1) * 4 + (u & 1)]     = (_Float16)q0;
    catH[(u >> 1) * 4 + 2 + (u & 1)] = (_Float16)q1;
  }
  __syncthreads();

  // ---- step 1: att_q partials via fdot2.  Thread (G,v): n quad 4v, d2 in [32G,+32).
  {
    const _Float16* wq = wsWqP + 8 * v;
    float4 a0 = {0,0,0,0}, a1 = {0,0,0,0};
    #pragma unroll 2
    for (int j2 = 0; j2 < 32; j2 += 2) {
      int d2 = 32 * G + j2;
      uint4 wp0 = *(const uint4*)(wq + (size_t)d2 * 1024);
      uint4 wp1 = *(const uint4*)(wq + (size_t)(d2 + 1) * 1024);
      uint4 cp2 = *(const uint4*)(&catH[d2 * 4]);
      dotq(a0, a1, wp0, cp2.x, cp2.y);
      dotq(a0, a1, wp1, cp2.z, cp2.w);
    }
    *(float4*)(&pt[G][0][4 * v]) = a0;
    *(float4*)(&pt[G][1][4 * v]) = a1;
  }
  __syncthreads();
  // combine: thread (qh,u): A = exp2(K2E * att_q); build pawF (fp16 quads)
  {
    float s = pt[0][qh][u] + pt[1][qh][u] + pt[2][qh][u] + pt[3][qh][u]
            + pt[4][qh][u] + pt[5][qh][u] + pt[6][qh][u] + pt[7][qh][u];
    float A = EXP2F(K2E * (s + b_q[u]));
    if (qh == 0) {
      pawF[u * 4 + 0] = (_Float16)A;
      pawF[u * 4 + 2] = (_Float16)w_att[u];
      pawF[u * 4 + 3] = (_Float16)0.f;
    } else {
      pawF[u * 4 + 1] = (_Float16)A;
    }
  }
  __syncthreads();

  // ---- step 2 (hot, fused): score partials (paired-rcp) + out-GEMM query half.
  //      Score: thread (G16,v6): k in [8v6,+8), n in [32*G16,+32).
  //      Fused out-q: thread (G,v): o quad 4v, c2 in [32G,+32)  (c<512: query).
  {
    const _Float16* ke = wsKeys + (size_t)b * MAT + 8 * v6;
    const _Float16* wo = wsWoutP + 8 * v;
    float4 s0a = {0,0,0,0}, s0b = {0,0,0,0};
    float4 s1a = {0,0,0,0}, s1b = {0,0,0,0};
    float4 o0 = {0,0,0,0}, o1 = {0,0,0,0};
    #pragma unroll 2
    for (int j = 0; j < 32; j += 2) {
      int n = 32 * G16 + j;
      uint4 Eu0 = *(const uint4*)(ke + (size_t)n * 512);
      uint4 Eu1 = *(const uint4*)(ke + (size_t)(n + 1) * 512);
      uint4 pw  = *(const uint4*)(&pawF[n * 4]);   // {A0,A1,w,pad}x2
      h2 Aab = u2h(pw.x);  float w0f = (float)u2h(pw.y).x;
      h2 Acd = u2h(pw.z);  float w1f = (float)u2h(pw.w).x;
      float A0n = (float)Aab.x, A1n = (float)Aab.y;
      float A0m = (float)Acd.x, A1m = (float)Acd.y;
      half4 E0lo = uu2h4(Eu0.x, Eu0.y), E0hi = uu2h4(Eu0.z, Eu0.w);
      half4 E1lo = uu2h4(Eu1.x, Eu1.y), E1hi = uu2h4(Eu1.z, Eu1.w);
      // pair (n, n+1): 1 rcp per 2 elements, per-k partials preserved
      s0a = scqp(s0a, E0lo, E1lo, A0n, A0m, w0f, w1f);
      s0b = scqp(s0b, E0hi, E1hi, A0n, A0m, w0f, w1f);
      s1a = scqp(s1a, E0lo, E1lo, A1n, A1m, w0f, w1f);
      s1b = scqp(s1b, E0hi, E1hi, A1n, A1m, w0f, w1f);
      // fused out-GEMM (query half): c2 = 32G+j, 32G+j+1
      int c2 = 32 * G + j;
      uint4 wp0 = *(const uint4*)(wo + (size_t)c2 * 1024);
      uint4 wp1 = *(const uint4*)(wo + (size_t)(c2 + 1) * 1024);
      uint4 cq2 = *(const uint4*)(&catH[c2 * 4]);
      dotq(o0, o1, wp0, cq2.x, cq2.y);
      dotq(o0, o1, wp1, cq2.z, cq2.w);
    }
    // conflict-free stores: ptH[qh][G16][8*v6..+8] = one half8 (b128) each
    half8 w0 = {(_Float16)s0a.x, (_Float16)s0a.y, (_Float16)s0a.z, (_Float16)s0a.w,
                (_Float16)s0b.x, (_Float16)s0b.y, (_Float16)s0b.z, (_Float16)s0b.w};
    half8 w1 = {(_Float16)s1a.x, (_Float16)s1a.y, (_Float16)s1a.z, (_Float16)s1a.w,
                (_Float16)s1b.x, (_Float16)s1b.y, (_Float16)s1b.z, (_Float16)s1b.w};
    *(half8*)(ptH + (size_t)G16 * 512 + 8 * v6)        = w0;
    *(half8*)(ptH + 8192 + (size_t)G16 * 512 + 8 * v6) = w1;
    *(float4*)(&pt2[G][0][4 * v]) = o0;
    *(float4*)(&pt2[G][1][4 * v]) = o1;
  }
  __syncthreads();

  // ---- softmax (no max-subtraction; batt+sumW cancels): thread (qh,u), k=u.
  {
    const _Float16* pp = ptH + qh * 8192 + u;   // stride 512 halves over G16
    float s = 0.f;
    #pragma unroll
    for (int g = 0; g < 16; ++g)
      s += (float)pp[g * 512];
    float e = EXP2F(-K2E * s);           // softmax weight (constants cancel)
    float se = waveRedSum(e);
    if (lane == 0) reds2[qh][wq8] = se;
    __syncthreads();
    float bs = reds2[qh][0]+reds2[qh][1]+reds2[qh][2]+reds2[qh][3]
             + reds2[qh][4]+reds2[qh][5]+reds2[qh][6]+reds2[qh][7];
    float pv = e * RCPF(bs);
    prH[(u >> 1) * 4 + qh * 2 + (u & 1)] = (_Float16)pv;
    probs[((size_t)(b * TQ + qabs0 + qh)) * TK + u] = pv;
  }
  __syncthreads();

  // ---- step 4: context partials via fdot2.  Thread (G,v): n quad 4v, k2 in [32G,+32).
  {
    const _Float16* vp = wsValP + (size_t)b * MAT + 8 * v;
    float4 c0 = {0,0,0,0}, c1 = {0,0,0,0};
    #pragma unroll 2
    for (int j2 = 0; j2 < 32; j2 += 2) {
      int k2 = 32 * G + j2;
      uint4 vk0 = *(const uint4*)(vp + (size_t)k2 * 1024);
      uint4 vk1 = *(const uint4*)(vp + (size_t)(k2 + 1) * 1024);
      uint4 pp2 = *(const uint4*)(&prH[k2 * 4]);
      dotq(c0, c1, vk0, pp2.x, pp2.y);
      dotq(c0, c1, vk1, pp2.z, pp2.w);
    }
    *(float4*)(&pt[G][0][4 * v]) = c0;
    *(float4*)(&pt[G][1][4 * v]) = c1;
  }
  __syncthreads();
  {
    float s = pt[0][qh][u] + pt[1][qh][u] + pt[2][qh][u] + pt[3][qh][u]
            + pt[4][qh][u] + pt[5][qh][u] + pt[6][qh][u] + pt[7][qh][u];
    catH[(256 + (u >> 1)) * 4 + qh * 2 + (u & 1)] = (_Float16)s;
  }
  __syncthreads();

  // ---- step 5 (ctx half only): thread (G,v): o quad 4v, c2 in [256+32G,+32).
  {
    const _Float16* wo = wsWoutP + 8 * v;
    float4 o0 = {0,0,0,0}, o1 = {0,0,0,0};
    #pragma unroll 2
    for (int j2 = 0; j2 < 32; j2 += 2) {
      int c2 = 256 + 32 * G + j2;
      uint4 wp0 = *(const uint4*)(wo + (size_t)c2 * 1024);
      uint4 wp1 = *(const uint4*)(wo + (size_t)(c2 + 1) * 1024);
      uint4 cp2 = *(const uint4*)(&catH[c2 * 4]);
      dotq(o0, o1, wp0, cp2.x, cp2.y);
      dotq(o0, o1, wp1, cp2.z, cp2.w);
    }
    *(float4*)(&pt[G][0][4 * v]) = o0;
    *(float4*)(&pt[G][1][4 * v]) = o1;
  }
  __syncthreads();
  {
    float sq = pt2[0][qh][u] + pt2[1][qh][u] + pt2[2][qh][u] + pt2[3][qh][u]
             + pt2[4][qh][u] + pt2[5][qh][u] + pt2[6][qh][u] + pt2[7][qh][u];
    float sc = pt[0][qh][u] + pt[1][qh][u] + pt[2][qh][u] + pt[3][qh][u]
             + pt[4][qh][u] + pt[5][qh][u] + pt[6][qh][u] + pt[7][qh][u];
    float oo = sq + sc + b_out[u];
    out[((size_t)(b * TQ + qabs0 + qh)) * OUTSZ + u] = fast_tanh(oo);
  }
}

// ---------------- round-6-style fallback (ws too small) ----------------------
__device__ __forceinline__ float sc4f(float4 w, float4 k, float4 a, float acc) {
  acc = fmaf(w.x, RCPF(EXP2F(fmaf(k.x, K2E, a.x)) + 1.0f), acc);
  acc = fmaf(w.y, RCPF(EXP2F(fmaf(k.y, K2E, a.y)) + 1.0f), acc);
  acc = fmaf(w.z, RCPF(EXP2F(fmaf(k.z, K2E, a.z)) + 1.0f), acc);
  acc = fmaf(w.w, RCPF(EXP2F(fmaf(k.w, K2E, a.w)) + 1.0f), acc);
  return acc;
}

__global__ __launch_bounds__(1024, 4)
void attn_fallback(const float* __restrict__ query, const float* __restrict__ keys,
                   const float* __restrict__ values, const float* __restrict__ W_q,
                   const float* __restrict__ b_q, const float* __restrict__ w_att,
                   const float* __restrict__ b_att, const float* __restrict__ W_out,
                   const float* __restrict__ b_out,
                   float* __restrict__ out, float* __restrict__ probs)
{
  __shared__ __align__(16) float qv[2][NN];
  __shared__ __align__(16) float aqc[2][NN];
  __shared__ __align__(16) float wv[NN];
  __shared__ __align__(16) float pr[2][TK];
  __shared__ __align__(16) float ctx[2][NN];
  __shared__ __align__(16) float part[2][2][NN];
  __shared__ float redm[2][8], reds[2][8], redw[8];

  const int t = threadIdx.x, H = t >> 9, u = t & 511;
  const int wave = t >> 6, lane = t & 63, wq8 = wave & 7;
  const int p = blockIdx.x, b = (p & 7) >> 1;
  const int qg = ((p >> 3) << 1) | (p & 1), qabs0 = qg * 2;
  const float batt = b_att[0];

  if (H == 0) wv[u] = w_att[u];
  qv[H][u] = query[((size_t)(b * TQ + qabs0 + H)) * NN + u];
  __syncthreads();
  if (H == 0) {
    float wp = waveRedSum(wv[u]);
    if (lane == 0) redw[wq8] = wp;
  }
  __syncthreads();
  const float sumW = redw[0]+redw[1]+redw[2]+redw[3]+redw[4]+redw[5]+redw[6]+redw[7];

  {
    const float4* wq4 = (const float4*)(W_q + (size_t)u * NN + 256 * H);
    const float4* x4  = (const float4*)(qv[0] + 256 * H);
    const float4* y4  = (const float4*)(qv[1] + 256 * H);
    float a0=0.f, a0b=0.f, a1=0.f, a1b=0.f;
    #pragma unroll 2
    for (int c = 0; c < 16; ++c) {
      float4 wA=wq4[4*c+0], wB=wq4[4*c+1], wC=wq4[4*c+2], wD=wq4[4*c+3];
      float4 xA=x4[4*c+0], xB=x4[4*c+1], xC=x4[4*c+2], xD=x4[4*c+3];
      a0 = fma4(wA,xA,a0); a0b = fma4(wB,xB,a0b);
      a0 = fma4(wC,xC,a0); a0b = fma4(wD,xD,a0b);
      float4 yA=y4[4*c+0], yB=y4[4*c+1], yC=y4[4*c+2], yD=y4[4*c+3];
      a1 = fma4(wA,yA,a1); a1b = fma4(wB,yB,a1b);
      a1 = fma4(wC,yC,a1); a1b = fma4(wD,yD,a1b);
    }
    part[H][0][u] = a0 + a0b; part[H][1][u] = a1 + a1b;
  }
  __syncthreads();
  aqc[H][u] = (part[0][H][u] + part[1][H][u] + b_q[u]) * K2E;
  __syncthreads();

  {
    const float4* kr  = (const float4*)(keys + ((size_t)(b * TK) + u) * NN + 256 * H);
    const float4* a0p = (const float4*)(aqc[0] + 256 * H);
    const float4* a1p = (const float4*)(aqc[1] + 256 * H);
    const float4* w4  = (const float4*)(wv + 256 * H);
    float s0 = 0.f, s1 = 0.f;
    #pragma unroll 2
    for (int c = 0; c < 16; ++c) {
      float4 kA=kr[4*c+0], kB=kr[4*c+1], kC=kr[4*c+2], kD=kr[4*c+3];
      float4 wA=w4[4*c+0], wB=w4[4*c+1], wC=w4[4*c+2], wD=w4[4*c+3];
      float4 aA=a0p[4*c+0], aB=a0p[4*c+1], aC=a0p[4*c+2], aD=a0p[4*c+3];
      s0 = sc4f(wA,kA,aA,s0); s0 = sc4f(wB,kB,aB,s0);
      s0 = sc4f(wC,kC,aC,s0); s0 = sc4f(wD,kD,aD,s0);
      float4 bA=a1p[4*c+0], bB=a1p[4*c+1], bC=a1p[4*c+2], bD=a1p[4*c+3];
      s1 = sc4f(wA,kA,bA,s1); s1 = sc4f(wB,kB,bB,s1);
      s1 = sc4f(wC,kC,bC,s1); s1 = sc4f(wD,kD,bD,s1);
    }
    part[H][0][u] = s0; part[H][1][u] = s1;
  }
  __syncthreads();

  {
    float sc = batt + sumW - 2.0f * (part[0][H][u] + part[1][H][u]);
    float m = sc;
    #pragma unroll
    for (int mm = 32; mm >= 1; mm >>= 1) m = fmaxf(m, __shfl_xor(m, mm, 64));
    if (lane == 0) redm[H][wq8] = m;
    __syncthreads();
    float bm = fmaxf(fmaxf(fmaxf(redm[H][0],redm[H][1]),fmaxf(redm[H][2],redm[H][3])),
                     fmaxf(fmaxf(redm[H][4],redm[H][5]),fmaxf(redm[H][6],redm[H][7])));
    float e = EXP2F((sc - bm) * L2E);
    float se = waveRedSum(e);
    if (lane == 0) reds[H][wq8] = se;
    __syncthreads();
    float bs = reds[H][0]+reds[H][1]+reds[H][2]+reds[H][3]
             + reds[H][4]+reds[H][5]+reds[H][6]+reds[H][7];
    float pv = e * RCPF(bs);
    pr[H][u] = pv;
    probs[((size_t)(b * TQ + qabs0 + H)) * TK + u] = pv;
  }
  __syncthreads();

  {
    const float* vcol = values + ((size_t)(b * TK) + 256 * H) * NN + u;
    const float4* p0 = (const float4*)(pr[0] + 256 * H);
    const float4* p1 = (const float4*)(pr[1] + 256 * H);
    float c0a=0.f, c0b=0.f, c1a=0.f, c1b=0.f;
    #pragma unroll 2
    for (int k = 0; k < 256; k += 8) {
      float v0 = vcol[(size_t)(k+0)*NN]; float v1 = vcol[(size_t)(k+1)*NN];
      float v2 = vcol[(size_t)(k+2)*NN]; float v3 = vcol[(size_t)(k+3)*NN];
      float v4 = vcol[(size_t)(k+4)*NN]; float v5 = vcol[(size_t)(k+5)*NN];
      float v6 = vcol[(size_t)(k+6)*NN]; float v7 = vcol[(size_t)(k+7)*NN];
      float4 pA = p0[k>>2], pB = p0[(k>>2)+1];
      float4 qA = p1[k>>2], qB = p1[(k>>2)+1];
      c0a = fmaf(pA.x,v0,c0a); c0a = fmaf(pA.y,v1,c0a);
      c0b = fmaf(pA.z,v2,c0b); c0b = fmaf(pA.w,v3,c0b);
      c0a = fmaf(pB.x,v4,c0a); c0a = fmaf(pB.y,v5,c0a);
      c0b = fmaf(pB.z,v6,c0b); c0b = fmaf(pB.w,v7,c0b);
      c1a = fmaf(qA.x,v0,c1a); c1a = fmaf(qA.y,v1,c1a);
      c1b = fmaf(qA.z,v2,c1b); c1b = fmaf(qA.w,v3,c1b);
      c1a = fmaf(qB.x,v4,c1a); c1a = fmaf(qB.y,v5,c1a);
      c1b = fmaf(qB.z,v6,c1b); c1b = fmaf(qB.w,v7,c1b);
    }
    part[H][0][u] = c0a + c0b; part[H][1][u] = c1a + c1b;
  }
  __syncthreads();
  ctx[H][u] = part[0][H][u] + part[1][H][u];
  __syncthreads();

  {
    const float4* wo = (const float4*)(W_out + (size_t)u * CATSZ + 512 * H);
    const float4* x4 = (H == 0) ? (const float4*)qv[0] : (const float4*)ctx[0];
    const float4* y4 = (H == 0) ? (const float4*)qv[1] : (const float4*)ctx[1];
    float o0=0.f, o0b=0.f, o1=0.f, o1b=0.f;
    #pragma unroll 2
    for (int c = 0; c < 32; ++c) {
      float4 wA=wo[4*c+0], wB=wo[4*c+1], wC=wo[4*c+2], wD=wo[4*c+3];
      float4 xA=x4[4*c+0], xB=x4[4*c+1], xC=x4[4*c+2], xD=x4[4*c+3];
      o0 = fma4(wA,xA,o0); o0b = fma4(wB,xB,o0b);
      o0 = fma4(wC,xC,o0); o0b = fma4(wD,xD,o0b);
      float4 yA=y4[4*c+0], yB=y4[4*c+1], yC=y4[4*c+2], yD=y4[4*c+3];
      o1 = fma4(wA,yA,o1); o1b = fma4(wB,yB,o1b);
      o1 = fma4(wC,yC,o1); o1b = fma4(wD,yD,o1b);
    }
    part[H][0][u] = o0 + o0b; part[H][1][u] = o1 + o1b;
  }
  __syncthreads();
  {
    float oo = part[0][H][u] + part[1][H][u] + b_out[u];
    out[((size_t)(b * TQ + qabs0 + H)) * OUTSZ + u] = fast_tanh(oo);
  }
}

extern "C" void kernel_launch(void* const* d_in, const int* in_sizes, int n_in,
                              void* d_out, int out_size, void* d_ws, size_t ws_size,
                              hipStream_t stream) {
  const float* query = (const float*)d_in[0];
  const float* keys  = (const float*)d_in[1];
  const float* vals  = (const float*)d_in[2];
  const float* W_q   = (const float*)d_in[3];
  const float* b_q   = (const float*)d_in[4];
  const float* w_att = (const float*)d_in[5];
  const float* b_att = (const float*)d_in[6];
  const float* W_out = (const float*)d_in[7];
  const float* b_out = (const float*)d_in[8];

  float* out   = (float*)d_out;
  float* probs = out + (size_t)BB * TQ * OUTSZ;

  if (ws_size >= (size_t)WS_HALVES * sizeof(_Float16)) {
    _Float16* ws = (_Float16*)d_ws;
    pack_kernel<<<dim3(2816), dim3(256), 0, stream>>>(keys, W_q, W_out, vals, ws);
    attn_main<<<dim3(BB * TQ / 2), dim3(1024), 0, stream>>>(
        query, b_q, w_att, b_att, b_out, ws, out, probs);
  } else {
    attn_fallback<<<dim3(BB * TQ / 2), dim3(1024), 0, stream>>>(
        query, keys, vals, W_q, b_q, w_att, b_att, W_out, b_out, out, probs);
  }
}